// Round 5
// baseline (847.062 us; speedup 1.0000x reference)
//
#include <hip/hip_runtime.h>

// FFT-based causal long convolution for (b=4, l=8192, d=1024) fp32.
// One workgroup per (b, d) pair. Real FFT of N=16384 as complex FFT of M=8192
// via even/odd packing.
//
// vs round 4 (454 us main dispatch, latency-bound at 20.8% occupancy):
//  - LDS halved to 32 KB by batched sub-FFT processing. After the first fused
//    5-stage register pass (DIF halves 4096..256) the transform decomposes
//    into 32 independent 256-point sub-FFTs; sub-FFT g is exactly p[g] across
//    the 256 threads. Spectrum pairing (k, M-k) respects parity (bit12 of
//    rev13(k) = bit0 of k): even-k entries live in sub-blocks 0..15, odd-k in
//    16..31. So the middle section (fwd passes + spectral multiply + inverse
//    passes) runs on HALF the array at a time in a 4096-point LDS buffer:
//    batch A = p[0..15] / even k, batch B = p[16..31] / odd k.
//  - Middle passes re-decomposed as 4+4 stages on 16-point groups (stride-16
//    then contiguous): 4096/16 = 256 groups per batch = 1 group/thread.
//  - __launch_bounds__(256, 4): 32 KB LDS + <=128 VGPR -> 4 blocks/CU
//    (16 waves/CU, 2x round-4 latency hiding); grid rounds 8 -> 4.
//  - filt_fft_kernel converted identically: 1024 blocks now co-resident in
//    ONE occupancy round.
//  - Unchanged: first/last global<->register fused passes, per-d filter
//    spectrum precompute in workspace, load-in-loop phase C (round-3 spill
//    lesson), bijective XCD swizzle, swz() LDS bank swizzle.

#define M 8192
#define NTH 256
#define MAXP 17           // ceil((M/2+1)/NTH)  (fallback kernel only)

__device__ __forceinline__ float2 cadd(float2 a, float2 b){ return make_float2(a.x+b.x, a.y+b.y); }
__device__ __forceinline__ float2 csub(float2 a, float2 b){ return make_float2(a.x-b.x, a.y-b.y); }
__device__ __forceinline__ float2 cmul(float2 a, float2 b){ return make_float2(a.x*b.x - a.y*b.y, a.x*b.y + a.y*b.x); }
__device__ __forceinline__ float2 conjf2(float2 a){ return make_float2(a.x, -a.y); }
__device__ __forceinline__ int rev13(int k){ return (int)(__brev((unsigned)k) >> 19); }
__device__ __forceinline__ int swz(int e){ return e ^ ((e >> 4) & 15) ^ ((e >> 8) & 15); }

static __device__ const float PI_F = 3.14159265358979323846f;

// cos/sin(pi*u/16); indexed with compile-time u in fully unrolled loops.
constexpr float CR_C[17] = {
  1.f, 0.98078528f, 0.92387953f, 0.83146961f, 0.70710678f,
  0.55557023f, 0.38268343f, 0.19509032f, 0.f, -0.19509032f,
  -0.38268343f, -0.55557023f, -0.70710678f, -0.83146961f,
  -0.92387953f, -0.98078528f, -1.f };
constexpr float CR_S[17] = {
  0.f, 0.19509032f, 0.38268343f, 0.55557023f, 0.70710678f,
  0.83146961f, 0.92387953f, 0.98078528f, 1.f, 0.98078528f,
  0.92387953f, 0.83146961f, 0.70710678f, 0.55557023f,
  0.38268343f, 0.19509032f, 0.f };

// a * e^{-i*pi*idx/16} (fwd) or a * e^{+i*pi*idx/16} (inv); idx compile-time.
__device__ __forceinline__ float2 cmul_cr(float2 a, int idx, bool inv) {
  if (idx == 0) return a;
  const float c = CR_C[idx], s = CR_S[idx];
  if (!inv) return make_float2(a.x*c + a.y*s, a.y*c - a.x*s);
  return make_float2(a.x*c - a.y*s, a.x*s + a.y*c);
}

// ---------------- 32-point fused pass (first / last, registers) ------------
// Group = { base + t*HS : t=0..31 }, r = base mod HS.
// Forward (DIF): halves 16HS..HS. Inverse (DIT): halves HS..16HS.
template<int HS, bool INV, bool FIRST_PAD, bool LAST_HALF>
__device__ __forceinline__ void fft5_regs(float2 (&p)[32], int r) {
  float s, c;
  const float th = PI_F * (float)r * (1.0f / (16.0f * (float)HS));
  __sincosf(INV ? th : -th, &s, &c);
  float2 w[5];
  w[0] = make_float2(c, s);
  w[1] = cmul(w[0], w[0]);
  w[2] = cmul(w[1], w[1]);
  w[3] = cmul(w[2], w[2]);
  w[4] = cmul(w[3], w[3]);
  if (!INV) {
#pragma unroll
    for (int st = 0; st < 5; ++st) {
      const int D = 16 >> st;
#pragma unroll
      for (int t0 = 0; t0 < 32; ++t0) {
        if ((t0 & D) == 0) {
          const int u = t0 & (D - 1);
          float2 a = p[t0];
          if (FIRST_PAD && st == 0) {
            p[t0 + D] = cmul_cr(cmul(a, w[0]), u, false);   // b==0
          } else {
            float2 b = p[t0 + D];
            p[t0] = cadd(a, b);
            p[t0 + D] = cmul_cr(cmul(csub(a, b), w[st]), u * (16 / D), false);
          }
        }
      }
    }
  } else {
#pragma unroll
    for (int st = 0; st < 5; ++st) {
      const int D = 1 << st;
#pragma unroll
      for (int t0 = 0; t0 < 32; ++t0) {
        if ((t0 & D) == 0) {
          const int u = t0 & (D - 1);
          float2 b = cmul_cr(cmul(p[t0 + D], w[4 - st]), u * (16 / D), true);
          float2 a = p[t0];
          p[t0] = cadd(a, b);
          if (!(LAST_HALF && st == 4)) p[t0 + D] = csub(a, b);
        }
      }
    }
  }
}

// ---------------- 16-point fused passes (batched middle section) -----------
// Stride-16 groups within a 4096-pt batch: group = {gl*256 + r + 16t},
// fwd halves 128..16, inv halves 16..128. w0 = e^{∓i*pi*r/128}.
template<bool INV>
__device__ __forceinline__ void fft4_regs(float2 (&p)[16], float2 w0) {
  float2 w[4];
  w[0] = w0;
  w[1] = cmul(w[0], w[0]);
  w[2] = cmul(w[1], w[1]);
  w[3] = cmul(w[2], w[2]);
  if (!INV) {
#pragma unroll
    for (int st = 0; st < 4; ++st) {
      const int D = 8 >> st;
#pragma unroll
      for (int t0 = 0; t0 < 16; ++t0) {
        if ((t0 & D) == 0) {
          const int u = t0 & (D - 1);
          float2 a = p[t0], b = p[t0 + D];
          p[t0] = cadd(a, b);
          p[t0 + D] = cmul_cr(cmul(csub(a, b), w[st]), u * (16 / D), false);
        }
      }
    }
  } else {
#pragma unroll
    for (int st = 0; st < 4; ++st) {
      const int D = 1 << st;
#pragma unroll
      for (int t0 = 0; t0 < 16; ++t0) {
        if ((t0 & D) == 0) {
          const int u = t0 & (D - 1);
          float2 b = cmul_cr(cmul(p[t0 + D], w[3 - st]), u * (16 / D), true);
          float2 a = p[t0];
          p[t0] = cadd(a, b);
          p[t0 + D] = csub(a, b);
        }
      }
    }
  }
}

// Contiguous 16-pt groups (r=0): fwd halves 8..1, inv halves 1..8. No sincos.
template<bool INV>
__device__ __forceinline__ void fft4c_regs(float2 (&p)[16]) {
  if (!INV) {
#pragma unroll
    for (int st = 0; st < 4; ++st) {
      const int D = 8 >> st;
#pragma unroll
      for (int t0 = 0; t0 < 16; ++t0) {
        if ((t0 & D) == 0) {
          const int u = t0 & (D - 1);
          float2 a = p[t0], b = p[t0 + D];
          p[t0] = cadd(a, b);
          p[t0 + D] = cmul_cr(csub(a, b), u * (16 / D), false);
        }
      }
    }
  } else {
#pragma unroll
    for (int st = 0; st < 4; ++st) {
      const int D = 1 << st;
#pragma unroll
      for (int t0 = 0; t0 < 16; ++t0) {
        if ((t0 & D) == 0) {
          const int u = t0 & (D - 1);
          float2 b = cmul_cr(p[t0 + D], u * (16 / D), true);
          float2 a = p[t0];
          p[t0] = cadd(a, b);
          p[t0 + D] = csub(a, b);
        }
      }
    }
  }
}

// Stride-16 pass over the 4096-pt batch buffer. 256 groups = 256 threads.
template<bool INV>
__device__ __forceinline__ void pass_s16(float2* LB, int tid) {
  const int r = tid & 15, gl = tid >> 4;
  const int base = gl * 256 + r;
  float2 q[16];
#pragma unroll
  for (int t = 0; t < 16; ++t) q[t] = LB[swz(base + 16 * t)];
  float s, c;
  const float th = PI_F * (float)r * (1.0f / 128.0f);
  __sincosf(INV ? th : -th, &s, &c);
  fft4_regs<INV>(q, make_float2(c, s));
#pragma unroll
  for (int t = 0; t < 16; ++t) LB[swz(base + 16 * t)] = q[t];
}

// Contiguous pass over the 4096-pt batch buffer. 256 groups = 256 threads.
template<bool INV>
__device__ __forceinline__ void pass_c16(float2* LB, int tid) {
  const int base = tid * 16;
  float2 q[16];
#pragma unroll
  for (int t = 0; t < 16; ++t) q[t] = LB[swz(base + t)];
  fft4c_regs<INV>(q);
#pragma unroll
  for (int t = 0; t < 16; ++t) LB[swz(base + t)] = q[t];
}

// One batch of the main pipeline: HALF=0 -> p[0..15], even k; HALF=1 ->
// p[16..31], odd k. LB is the 4096-pt (32 KB) buffer.
template<int HALF>
__device__ __forceinline__ void conv_batch(float2* LB, float2 (&p)[32],
                                           int tid, const float4* kfp) {
#pragma unroll
  for (int g = 0; g < 16; ++g) LB[swz(g * 256 + tid)] = p[HALF * 16 + g];
  __syncthreads();
  pass_s16<false>(LB, tid);                  // halves 128..16
  __syncthreads();
  pass_c16<false>(LB, tid);                  // halves 8..1
  __syncthreads();
  constexpr int NQ = (HALF == 0) ? 9 : 8;    // even k includes k=4096
#pragma unroll
  for (int q = 0; q < NQ; ++q) {
    int kp = tid + 256 * q;
    int k = 2 * kp + HALF;
    if (k <= M / 2) {
      float4 kv = kfp[k];                    // short-lived, per-iteration
      int rk  = rev13(k) - HALF * 4096;      // local position in batch
      int rmk = rev13((M - k) & (M - 1)) - HALF * 4096;
      float2 Zk = LB[swz(rk)], Zmk = LB[swz(rmk)];
      float2 Ze = make_float2(0.5f*(Zk.x + Zmk.x), 0.5f*(Zk.y - Zmk.y));
      float2 t  = make_float2(Zk.x - Zmk.x, Zk.y + Zmk.y);
      float2 Zo = make_float2(0.5f*t.y, -0.5f*t.x);
      float s, c; __sincosf(-PI_F * (float)k * (1.0f/(float)M), &s, &c);
      float2 W = make_float2(c, s);
      float2 WZo = cmul(W, Zo);
      float2 Uk  = cadd(Ze, WZo);
      float2 Umk = conjf2(csub(Ze, WZo));
      float2 Yk  = cmul(Uk,  make_float2(kv.x, kv.y));
      float2 Ymk = cmul(Umk, make_float2(kv.z, kv.w));
      float2 Ye  = make_float2(0.5f*(Yk.x + Ymk.x), 0.5f*(Yk.y - Ymk.y));
      float2 t2  = make_float2(0.5f*(Yk.x - Ymk.x), 0.5f*(Yk.y + Ymk.y));
      float2 Zoy = cmul(conjf2(W), t2);
      float2 Zyk  = make_float2(Ye.x - Zoy.y, Ye.y + Zoy.x);
      float2 Zymk = make_float2(Ye.x + Zoy.y, Zoy.x - Ye.y);
      LB[swz(rk)]  = Zyk;
      LB[swz(rmk)] = Zymk;                   // k==0 / k==4096: same slot, same value
    }
  }
  __syncthreads();
  pass_c16<true>(LB, tid);                   // halves 1..8
  __syncthreads();
  pass_s16<true>(LB, tid);                   // halves 16..128
  __syncthreads();
#pragma unroll
  for (int g = 0; g < 16; ++g) p[HALF * 16 + g] = LB[swz(g * 256 + tid)];
  __syncthreads();                           // reads done before next batch
}

// Filter-FFT batch: forward only + spectrum extract to workspace.
template<int HALF>
__device__ __forceinline__ void filt_batch(float2* LB, float2 (&p)[32],
                                           int tid, float4* out) {
#pragma unroll
  for (int g = 0; g < 16; ++g) LB[swz(g * 256 + tid)] = p[HALF * 16 + g];
  __syncthreads();
  pass_s16<false>(LB, tid);
  __syncthreads();
  pass_c16<false>(LB, tid);
  __syncthreads();
  constexpr int NQ = (HALF == 0) ? 9 : 8;
#pragma unroll
  for (int q = 0; q < NQ; ++q) {
    int kp = tid + 256 * q;
    int k = 2 * kp + HALF;
    if (k <= M / 2) {
      int rk  = rev13(k) - HALF * 4096;
      int rmk = rev13((M - k) & (M - 1)) - HALF * 4096;
      float2 Zk = LB[swz(rk)], Zmk = LB[swz(rmk)];
      float2 Ze = make_float2(0.5f*(Zk.x + Zmk.x), 0.5f*(Zk.y - Zmk.y));
      float2 t  = make_float2(Zk.x - Zmk.x, Zk.y + Zmk.y);
      float2 Zo = make_float2(0.5f*t.y, -0.5f*t.x);
      float s, c; __sincosf(-PI_F * (float)k * (1.0f/(float)M), &s, &c);
      float2 W = make_float2(c, s);
      float2 WZo = cmul(W, Zo);
      float2 Kk = cadd(Ze, WZo);
      float2 Km = conjf2(csub(Ze, WZo));
      out[k] = make_float4(Kk.x, Kk.y, Km.x, Km.y);
    }
  }
  __syncthreads();                           // reads done before next batch
}

// Precompute per-d filter spectrum: (K[k], K[M-k]) for k=0..M/2 as float4.
__global__ __launch_bounds__(NTH, 4)
void filt_fft_kernel(const float* __restrict__ filt, float4* __restrict__ kf) {
  __shared__ float2 LB[4096];                // 32 KB
  const int tid = threadIdx.x;
  const int d = blockIdx.x;
  const float* fp = filt + (size_t)d * 8192;
  float2 p[32];
#pragma unroll
  for (int t = 0; t < 16; ++t) {
    int m = tid + t * NTH;
    p[t] = make_float2(fp[2*m], fp[2*m + 1]);
  }
#pragma unroll
  for (int t = 16; t < 32; ++t) p[t] = make_float2(0.f, 0.f);
  fft5_regs<256, false, true, false>(p, tid);      // halves 4096..256
  float4* out = kf + (size_t)d * (M/2 + 1);
  filt_batch<0>(LB, p, tid, out);
  filt_batch<1>(LB, p, tid, out);
}

// ---------------- HOT KERNEL: requires kf ----------------------------------
__global__ __launch_bounds__(NTH, 4)
void longconv_kf_kernel(const float* __restrict__ x,
                        const float4* __restrict__ kf,
                        float* __restrict__ y) {
  __shared__ float2 LB[4096];                // 32 KB
  const int tid = threadIdx.x;

  // Bijective XCD swizzle: XCD j owns 512 consecutive blk = one b-group,
  // consecutive d -> co-resident blocks share x/y cache lines in its L2.
  const int nwg = gridDim.x;                 // 4096, multiple of 8
  const int cpx = nwg >> 3;
  const int bid = blockIdx.x;
  const int blk = (bid & 7) * cpx + (bid >> 3);
  const int d = blk & 1023;
  const int b = blk >> 10;

  // ---------------- Phase B: signal FFT, first pass in registers ----------
  float2 p[32];
  {
    const float* xp = x + (size_t)b * (8192 * 1024) + d;
#pragma unroll
    for (int t = 0; t < 16; ++t) {
      int m = tid + t * NTH;
      p[t] = make_float2(xp[(size_t)(2*m)     * 1024],
                         xp[(size_t)(2*m + 1) * 1024]);
    }
#pragma unroll
    for (int t = 16; t < 32; ++t) p[t] = make_float2(0.f, 0.f);
    fft5_regs<256, false, true, false>(p, tid);    // halves 4096..256
  }

  // ---------------- Batched middle section (fwd + multiply + inv) ---------
  const float4* kfp = kf + (size_t)d * (M/2 + 1);
  conv_batch<0>(LB, p, tid, kfp);            // sub-blocks 0..15, even k
  conv_batch<1>(LB, p, tid, kfp);            // sub-blocks 16..31, odd k

  // ---------------- Final inverse pass + direct register store of y -------
  {
    fft5_regs<256, true, false, true>(p, tid);     // halves 256..4096
    float* yp = y + (size_t)b * (8192 * 1024) + d;
    const float inv = 1.0f / (float)M;
#pragma unroll
    for (int t = 0; t < 16; ++t) {
      int m = tid + t * NTH;                 // first l samples (packed pairs)
      yp[(size_t)(2*m)     * 1024] = p[t].x * inv;
      yp[(size_t)(2*m + 1) * 1024] = p[t].y * inv;
    }
  }
}

// ---------------- FALLBACK: no workspace (64 KB LDS, round-4 structure) ----
template<bool INV>
__device__ __forceinline__ void pass5_lds(float2* L, int tid) {
  const int r = tid & 7;
  const int base = ((tid - r) << 5) + r;
  float2 p[32];
#pragma unroll
  for (int t = 0; t < 32; ++t) p[t] = L[swz(base + t * 8)];
  fft5_regs<8, INV, false, false>(p, r);
#pragma unroll
  for (int t = 0; t < 32; ++t) L[swz(base + t * 8)] = p[t];
}

template<bool INV>
__device__ __forceinline__ void pass3_lds(float2* L, int tid) {
#pragma unroll
  for (int g = 0; g < 4; ++g) {
    const int base = tid * 32 + g * 8;
    float2 p[8];
#pragma unroll
    for (int t = 0; t < 8; ++t) p[t] = L[swz(base + t)];
    if (!INV) {
#pragma unroll
      for (int st = 0; st < 3; ++st) {
        const int D = 4 >> st;
#pragma unroll
        for (int t0 = 0; t0 < 8; ++t0) {
          if ((t0 & D) == 0) {
            const int u = t0 & (D - 1);
            float2 a = p[t0], b = p[t0 + D];
            p[t0] = cadd(a, b);
            p[t0 + D] = cmul_cr(csub(a, b), u * (16 / D), false);
          }
        }
      }
    } else {
#pragma unroll
      for (int st = 0; st < 3; ++st) {
        const int D = 1 << st;
#pragma unroll
        for (int t0 = 0; t0 < 8; ++t0) {
          if ((t0 & D) == 0) {
            const int u = t0 & (D - 1);
            float2 b = cmul_cr(p[t0 + D], u * (16 / D), true);
            float2 a = p[t0];
            p[t0] = cadd(a, b);
            p[t0 + D] = csub(a, b);
          }
        }
      }
    }
#pragma unroll
    for (int t = 0; t < 8; ++t) L[swz(base + t)] = p[t];
  }
}

__global__ __launch_bounds__(NTH, 2)
void longconv_fallback_kernel(const float* __restrict__ x,
                              const float* __restrict__ filt,
                              float* __restrict__ y) {
  __shared__ float2 L[M];
  const int tid = threadIdx.x;
  const int nwg = gridDim.x;
  const int cpx = nwg >> 3;
  const int bid = blockIdx.x;
  const int blk = (bid & 7) * cpx + (bid >> 3);
  const int d = blk & 1023;
  const int b = blk >> 10;

  float2 Kk[MAXP], Kmk[MAXP];

  {
    const float* fp = filt + (size_t)d * 8192;
    float2 p[32];
#pragma unroll
    for (int t = 0; t < 16; ++t) {
      int m = tid + t * NTH;
      p[t] = make_float2(fp[2*m], fp[2*m + 1]);
    }
#pragma unroll
    for (int t = 16; t < 32; ++t) p[t] = make_float2(0.f, 0.f);
    fft5_regs<256, false, true, false>(p, tid);
#pragma unroll
    for (int t = 0; t < 32; ++t) L[swz(tid + t * 256)] = p[t];
  }
  __syncthreads();
  pass5_lds<false>(L, tid);
  __syncthreads();
  pass3_lds<false>(L, tid);
  __syncthreads();
#pragma unroll
  for (int pq = 0; pq < MAXP; ++pq) {
    int k = tid + pq * NTH;
    if (k <= M/2) {
      int rk  = rev13(k);
      int rmk = rev13((M - k) & (M - 1));
      float2 Zk = L[swz(rk)], Zmk = L[swz(rmk)];
      float2 Ze = make_float2(0.5f*(Zk.x + Zmk.x), 0.5f*(Zk.y - Zmk.y));
      float2 t  = make_float2(Zk.x - Zmk.x, Zk.y + Zmk.y);
      float2 Zo = make_float2(0.5f*t.y, -0.5f*t.x);
      float s, c; __sincosf(-PI_F * (float)k * (1.0f/(float)M), &s, &c);
      float2 W = make_float2(c, s);
      float2 WZo = cmul(W, Zo);
      Kk[pq]  = cadd(Ze, WZo);
      Kmk[pq] = conjf2(csub(Ze, WZo));
    }
  }
  __syncthreads();

  {
    const float* xp = x + (size_t)b * (8192 * 1024) + d;
    float2 p[32];
#pragma unroll
    for (int t = 0; t < 16; ++t) {
      int m = tid + t * NTH;
      p[t] = make_float2(xp[(size_t)(2*m)     * 1024],
                         xp[(size_t)(2*m + 1) * 1024]);
    }
#pragma unroll
    for (int t = 16; t < 32; ++t) p[t] = make_float2(0.f, 0.f);
    fft5_regs<256, false, true, false>(p, tid);
#pragma unroll
    for (int t = 0; t < 32; ++t) L[swz(tid + t * 256)] = p[t];
  }
  __syncthreads();
  pass5_lds<false>(L, tid);
  __syncthreads();
  pass3_lds<false>(L, tid);
  __syncthreads();

#pragma unroll
  for (int pq = 0; pq < MAXP; ++pq) {
    int k = tid + pq * NTH;
    if (k <= M/2) {
      int rk  = rev13(k);
      int rmk = rev13((M - k) & (M - 1));
      float2 Zk = L[swz(rk)], Zmk = L[swz(rmk)];
      float2 Ze = make_float2(0.5f*(Zk.x + Zmk.x), 0.5f*(Zk.y - Zmk.y));
      float2 t  = make_float2(Zk.x - Zmk.x, Zk.y + Zmk.y);
      float2 Zo = make_float2(0.5f*t.y, -0.5f*t.x);
      float s, c; __sincosf(-PI_F * (float)k * (1.0f/(float)M), &s, &c);
      float2 W = make_float2(c, s);
      float2 WZo = cmul(W, Zo);
      float2 Uk  = cadd(Ze, WZo);
      float2 Umk = conjf2(csub(Ze, WZo));
      float2 Yk  = cmul(Uk,  Kk[pq]);
      float2 Ymk = cmul(Umk, Kmk[pq]);
      float2 Ye  = make_float2(0.5f*(Yk.x + Ymk.x), 0.5f*(Yk.y - Ymk.y));
      float2 t2  = make_float2(0.5f*(Yk.x - Ymk.x), 0.5f*(Yk.y + Ymk.y));
      float2 Zoy = cmul(conjf2(W), t2);
      float2 Zyk  = make_float2(Ye.x - Zoy.y, Ye.y + Zoy.x);
      float2 Zymk = make_float2(Ye.x + Zoy.y, Zoy.x - Ye.y);
      L[swz(rk)]  = Zyk;
      L[swz(rmk)] = Zymk;
    }
  }
  __syncthreads();

  pass3_lds<true>(L, tid);
  __syncthreads();
  pass5_lds<true>(L, tid);
  __syncthreads();

  {
    float2 p[32];
#pragma unroll
    for (int t = 0; t < 32; ++t) p[t] = L[swz(tid + t * 256)];
    fft5_regs<256, true, false, true>(p, tid);
    float* yp = y + (size_t)b * (8192 * 1024) + d;
    const float inv = 1.0f / (float)M;
#pragma unroll
    for (int t = 0; t < 16; ++t) {
      int m = tid + t * NTH;
      yp[(size_t)(2*m)     * 1024] = p[t].x * inv;
      yp[(size_t)(2*m + 1) * 1024] = p[t].y * inv;
    }
  }
}

extern "C" void kernel_launch(void* const* d_in, const int* in_sizes, int n_in,
                              void* d_out, int out_size, void* d_ws, size_t ws_size,
                              hipStream_t stream) {
  const float* x    = (const float*)d_in[0];   // (b, l, d) fp32
  const float* filt = (const float*)d_in[1];   // (d, l) fp32
  float* y = (float*)d_out;                    // (b, l, d) fp32

  const int D = 1024, Lseq = 8192;
  const int B = in_sizes[0] / (D * Lseq);      // 4

  const size_t kf_bytes = (size_t)D * (M/2 + 1) * sizeof(float4);  // ~67 MB
  dim3 grid(B * D), block(NTH);

  if (d_ws != nullptr && ws_size >= kf_bytes) {
    hipLaunchKernelGGL(filt_fft_kernel, dim3(D), dim3(NTH), 0, stream,
                       filt, (float4*)d_ws);
    hipLaunchKernelGGL(longconv_kf_kernel, grid, block, 0, stream,
                       x, (const float4*)d_ws, y);
  } else {
    hipLaunchKernelGGL(longconv_fallback_kernel, grid, block, 0, stream,
                       x, filt, y);
  }
}